// Round 1
// baseline (970.459 us; speedup 1.0000x reference)
//
#include <hip/hip_runtime.h>
#include <hip/hip_bf16.h>
#include <math.h>

// Problem constants (B=4, S=4096 -> T=16384 tokens)
#define TOKENS 16384
#define HD 1024
#define FD 2048
#define NEXP 8
#define RP_MAX (264 * 128)   // max padded routed rows (sum ceil(c_e/128)*128 <= 264*128)
#define MAX_MT 264           // max 128-row m-tiles across all experts

typedef __bf16 bf16x8 __attribute__((ext_vector_type(8)));
typedef float f32x4 __attribute__((ext_vector_type(4)));
typedef unsigned short u16;
typedef unsigned int u32;

__device__ __forceinline__ u16 f2bf(float f) {
    union { float f; u32 u; } v; v.f = f;
    return (u16)((v.u + 0x7FFFu + ((v.u >> 16) & 1u)) >> 16);
}

__device__ __forceinline__ void gload_lds16(const void* g, void* l) {
    __builtin_amdgcn_global_load_lds(
        (const __attribute__((address_space(1))) u32*)g,
        (__attribute__((address_space(3))) u32*)l, 16, 0, 0);
}

// ---------------- routing ----------------

__global__ void init_routing(int* sorted_rid, int* counts, int* fill, int* numTiles) {
    int i = blockIdx.x * blockDim.x + threadIdx.x;
    if (i < RP_MAX) sorted_rid[i] = -1;
    if (i < NEXP) { counts[i] = 0; fill[i] = 0; }
    if (i == 0) *numTiles = 0;
}

__global__ void zero_f32(float4* p, int n4) {
    int i = blockIdx.x * blockDim.x + threadIdx.x;
    if (i < n4) p[i] = make_float4(0.f, 0.f, 0.f, 0.f);
}

__global__ void count_kernel(const int* __restrict__ te, int* counts) {
    int j = blockIdx.x * blockDim.x + threadIdx.x;
    if (j < TOKENS * 2) atomicAdd(&counts[te[j]], 1);
}

__global__ void scan_kernel(const int* __restrict__ counts, int* offs,
                            int* tileE, int* tileRow, int* numTiles) {
    if (blockIdx.x == 0 && threadIdx.x == 0) {
        int o = 0, t = 0;
        for (int e = 0; e < NEXP; e++) {
            offs[e] = o;
            int nt = (counts[e] + 127) >> 7;
            for (int i = 0; i < nt; i++) { tileE[t] = e; tileRow[t] = o + i * 128; t++; }
            o += nt * 128;
        }
        *numTiles = t;
    }
}

__global__ void scatter_kernel(const int* __restrict__ te, const int* __restrict__ offs,
                               int* fill, int* sorted_rid) {
    int j = blockIdx.x * blockDim.x + threadIdx.x;
    if (j < TOKENS * 2) {
        int e = te[j];
        int p = offs[e] + atomicAdd(&fill[e], 1);
        sorted_rid[p] = j;
    }
}

// ---------------- conversions ----------------

__global__ void convert_x(const float* __restrict__ x, u16* __restrict__ xb) {
    int i = blockIdx.x * blockDim.x + threadIdx.x;   // one thread = 8 elems
    const float4* xv = (const float4*)x;
    float4 a = xv[i * 2], b = xv[i * 2 + 1];
    union { u16 s[8]; uint4 v; } o;
    o.s[0] = f2bf(a.x); o.s[1] = f2bf(a.y); o.s[2] = f2bf(a.z); o.s[3] = f2bf(a.w);
    o.s[4] = f2bf(b.x); o.s[5] = f2bf(b.y); o.s[6] = f2bf(b.z); o.s[7] = f2bf(b.w);
    *(uint4*)(xb + (size_t)i * 8) = o.v;
}

// in: [E][K][N] f32  ->  out: [E][N][K] bf16
__global__ void transpose_conv(const float* __restrict__ in, u16* __restrict__ out,
                               int K, int N) {
    __shared__ float tile[32][33];
    int e = blockIdx.z;
    int n0 = blockIdx.x * 32, k0 = blockIdx.y * 32;
    const float* src = in + (size_t)e * K * N;
    u16* dst = out + (size_t)e * N * K;
    int tx = threadIdx.x, ty = threadIdx.y;
    #pragma unroll
    for (int j = 0; j < 32; j += 8)
        tile[ty + j][tx] = src[(size_t)(k0 + ty + j) * N + n0 + tx];
    __syncthreads();
    #pragma unroll
    for (int j = 0; j < 32; j += 8)
        dst[(size_t)(n0 + ty + j) * K + k0 + tx] = f2bf(tile[tx][ty + j]);
}

// ---------------- grouped GEMM 1: H_act = gelu(X[gather] @ w1 + b1) ----------------
// A: gathered X rows [128 x K=1024] bf16, B: W1t [E][F][H] (n-major, k-contig)

__global__ __launch_bounds__(256, 2) void gemm1_kernel(
    const u16* __restrict__ Xb, const u16* __restrict__ W1t,
    const float* __restrict__ b1, const int* __restrict__ sorted_rid,
    const int* __restrict__ tileE, const int* __restrict__ tileRow,
    const int* __restrict__ numTiles, u16* __restrict__ Hact)
{
    int mt = blockIdx.x;
    if (mt >= *numTiles) return;
    int e = tileE[mt];
    int row0 = tileRow[mt];
    int n0 = blockIdx.y * 128;

    __shared__ __align__(16) u16 As[128 * 64];
    __shared__ __align__(16) u16 Bs[128 * 64];

    int tid = threadIdx.x;
    int wave = tid >> 6, lane = tid & 63;

    const u16* gA[4]; const u16* gB[4];
    #pragma unroll
    for (int i = 0; i < 4; i++) {
        int c = i * 256 + tid;
        int r = c >> 3, kc = c & 7;
        int rid = sorted_rid[row0 + r];
        int tok = rid < 0 ? 0 : (rid >> 1);
        gA[i] = Xb + (size_t)tok * HD + kc * 8;
        gB[i] = W1t + ((size_t)e * FD + (n0 + r)) * HD + kc * 8;
    }
    char* AsB = (char*)As; char* BsB = (char*)Bs;

    f32x4 acc[4][4] = {};

    int wr = wave >> 1, wc = wave & 1;
    const u16* Arow = As + ((wr * 64 + (lane & 15)) * 64 + (lane >> 4) * 8);
    const u16* Brow = Bs + ((wc * 64 + (lane & 15)) * 64 + (lane >> 4) * 8);

    for (int kt = 0; kt < HD / 64; kt++) {
        #pragma unroll
        for (int i = 0; i < 4; i++)
            gload_lds16(gA[i], AsB + i * 4096 + wave * 1024);
        #pragma unroll
        for (int i = 0; i < 4; i++)
            gload_lds16(gB[i], BsB + i * 4096 + wave * 1024);
        #pragma unroll
        for (int i = 0; i < 4; i++) { gA[i] += 64; gB[i] += 64; }
        __syncthreads();   // drains vmcnt(0) -> staged tile visible
        #pragma unroll
        for (int kk = 0; kk < 2; kk++) {
            bf16x8 a[4], b[4];
            #pragma unroll
            for (int m = 0; m < 4; m++) a[m] = *(const bf16x8*)(Arow + m * 1024 + kk * 32);
            #pragma unroll
            for (int n = 0; n < 4; n++) b[n] = *(const bf16x8*)(Brow + n * 1024 + kk * 32);
            #pragma unroll
            for (int m = 0; m < 4; m++)
                #pragma unroll
                for (int n = 0; n < 4; n++)
                    acc[m][n] = __builtin_amdgcn_mfma_f32_16x16x32_bf16(a[m], b[n], acc[m][n], 0, 0, 0);
        }
        __syncthreads();   // all waves done reading before next stage
    }

    // epilogue: bias + exact gelu -> bf16 store
    const float* b1e = b1 + e * FD + n0;
    #pragma unroll
    for (int n = 0; n < 4; n++) {
        int col = wc * 64 + n * 16 + (lane & 15);
        float bias = b1e[col];
        #pragma unroll
        for (int m = 0; m < 4; m++) {
            int rbase = wr * 64 + m * 16 + (lane >> 4) * 4;
            #pragma unroll
            for (int r = 0; r < 4; r++) {
                float v = acc[m][n][r] + bias;
                v = 0.5f * v * (1.0f + erff(v * 0.70710678118f));
                Hact[(size_t)(row0 + rbase + r) * FD + n0 + col] = f2bf(v);
            }
        }
    }
}

// ---------------- grouped GEMM 2: y += fw * (H_act @ w2 + b2) ----------------
// A: Hact [rows x K=2048] bf16 (contig), B: W2t [E][H][F] (n-major, k-contig)

__global__ __launch_bounds__(256, 2) void gemm2_kernel(
    const u16* __restrict__ Hact, const u16* __restrict__ W2t,
    const float* __restrict__ b2, const float* __restrict__ ew,
    const int* __restrict__ sorted_rid,
    const int* __restrict__ tileE, const int* __restrict__ tileRow,
    const int* __restrict__ numTiles, float* __restrict__ y)
{
    int mt = blockIdx.x;
    if (mt >= *numTiles) return;
    int e = tileE[mt];
    int row0 = tileRow[mt];
    int n0 = blockIdx.y * 128;

    __shared__ __align__(16) u16 As[128 * 64];
    __shared__ __align__(16) u16 Bs[128 * 64];

    int tid = threadIdx.x;
    int wave = tid >> 6, lane = tid & 63;

    const u16* gA[4]; const u16* gB[4];
    #pragma unroll
    for (int i = 0; i < 4; i++) {
        int c = i * 256 + tid;
        int r = c >> 3, kc = c & 7;
        gA[i] = Hact + (size_t)(row0 + r) * FD + kc * 8;
        gB[i] = W2t + ((size_t)e * HD + (n0 + r)) * FD + kc * 8;
    }
    char* AsB = (char*)As; char* BsB = (char*)Bs;

    f32x4 acc[4][4] = {};

    int wr = wave >> 1, wc = wave & 1;
    const u16* Arow = As + ((wr * 64 + (lane & 15)) * 64 + (lane >> 4) * 8);
    const u16* Brow = Bs + ((wc * 64 + (lane & 15)) * 64 + (lane >> 4) * 8);

    for (int kt = 0; kt < FD / 64; kt++) {
        #pragma unroll
        for (int i = 0; i < 4; i++)
            gload_lds16(gA[i], AsB + i * 4096 + wave * 1024);
        #pragma unroll
        for (int i = 0; i < 4; i++)
            gload_lds16(gB[i], BsB + i * 4096 + wave * 1024);
        #pragma unroll
        for (int i = 0; i < 4; i++) { gA[i] += 64; gB[i] += 64; }
        __syncthreads();
        #pragma unroll
        for (int kk = 0; kk < 2; kk++) {
            bf16x8 a[4], b[4];
            #pragma unroll
            for (int m = 0; m < 4; m++) a[m] = *(const bf16x8*)(Arow + m * 1024 + kk * 32);
            #pragma unroll
            for (int n = 0; n < 4; n++) b[n] = *(const bf16x8*)(Brow + n * 1024 + kk * 32);
            #pragma unroll
            for (int m = 0; m < 4; m++)
                #pragma unroll
                for (int n = 0; n < 4; n++)
                    acc[m][n] = __builtin_amdgcn_mfma_f32_16x16x32_bf16(a[m], b[n], acc[m][n], 0, 0, 0);
        }
        __syncthreads();
    }

    // epilogue: bias, routing weight, atomic scatter-add into y[token]
    const float* b2e = b2 + e * HD + n0;
    #pragma unroll
    for (int m = 0; m < 4; m++) {
        int rbase = wr * 64 + m * 16 + (lane >> 4) * 4;
        #pragma unroll
        for (int r = 0; r < 4; r++) {
            int rid = sorted_rid[row0 + rbase + r];
            if (rid < 0) continue;               // padding row
            float fw = ew[rid];
            float* yrow = y + (size_t)(rid >> 1) * HD + n0;
            #pragma unroll
            for (int n = 0; n < 4; n++) {
                int col = wc * 64 + n * 16 + (lane & 15);
                float v = (acc[m][n][r] + b2e[col]) * fw;
                atomicAdd(&yrow[col], v);
            }
        }
    }
}

// ---------------- launch ----------------

extern "C" void kernel_launch(void* const* d_in, const int* in_sizes, int n_in,
                              void* d_out, int out_size, void* d_ws, size_t ws_size,
                              hipStream_t stream) {
    const float* x  = (const float*)d_in[0];
    const float* ew = (const float*)d_in[1];
    const int*   te = (const int*)d_in[2];
    const float* w1 = (const float*)d_in[3];
    const float* b1 = (const float*)d_in[4];
    const float* w2 = (const float*)d_in[5];
    const float* b2 = (const float*)d_in[6];
    float* y = (float*)d_out;

    char* ws = (char*)d_ws;
    u16* Xb   = (u16*)(ws);                      // 33,554,432 B
    u16* W1t  = (u16*)(ws + 33554432);           // 33,554,432 B
    u16* W2t  = (u16*)(ws + 67108864);           // 33,554,432 B
    u16* Hact = (u16*)(ws + 100663296);          // 138,412,032 B
    char* ip  = ws + 239075328;
    int* counts   = (int*)(ip);
    int* fill     = (int*)(ip + 32);
    int* offs     = (int*)(ip + 64);
    int* numTiles = (int*)(ip + 96);
    int* tileE    = (int*)(ip + 128);
    int* tileRow  = (int*)(ip + 128 + 1056);
    int* sorted   = (int*)(ip + 4096);           // RP_MAX ints

    // routing
    init_routing<<<(RP_MAX + 255) / 256, 256, 0, stream>>>(sorted, counts, fill, numTiles);
    zero_f32<<<(out_size / 4 + 255) / 256, 256, 0, stream>>>((float4*)y, out_size / 4);
    count_kernel<<<(TOKENS * 2 + 255) / 256, 256, 0, stream>>>(te, counts);
    scan_kernel<<<1, 64, 0, stream>>>(counts, offs, tileE, tileRow, numTiles);
    scatter_kernel<<<(TOKENS * 2 + 255) / 256, 256, 0, stream>>>(te, offs, fill, sorted);

    // conversions
    convert_x<<<(TOKENS * HD / 8 + 255) / 256, 256, 0, stream>>>(x, Xb);
    transpose_conv<<<dim3(FD / 32, HD / 32, NEXP), dim3(32, 8), 0, stream>>>(w1, W1t, HD, FD);
    transpose_conv<<<dim3(HD / 32, FD / 32, NEXP), dim3(32, 8), 0, stream>>>(w2, W2t, FD, HD);

    // grouped GEMMs
    gemm1_kernel<<<dim3(MAX_MT, FD / 128), 256, 0, stream>>>(
        Xb, W1t, b1, sorted, tileE, tileRow, numTiles, Hact);
    gemm2_kernel<<<dim3(MAX_MT, HD / 128), 256, 0, stream>>>(
        Hact, W2t, b2, ew, sorted, tileE, tileRow, numTiles, y);
}

// Round 2
// 929.322 us; speedup vs baseline: 1.0443x; 1.0443x over previous
//
#include <hip/hip_runtime.h>
#include <hip/hip_bf16.h>
#include <math.h>

// Problem constants (B=4, S=4096 -> T=16384 tokens)
#define TOKENS 16384
#define HD 1024
#define FD 2048
#define NEXP 8
#define RP_MAX (264 * 128)   // max padded routed rows (sum ceil(c_e/128)*128 <= 264*128)
#define MAX_MT 264           // max 128-row m-tiles across all experts

typedef __bf16 bf16x8 __attribute__((ext_vector_type(8)));
typedef float f32x4 __attribute__((ext_vector_type(4)));
typedef unsigned short u16;
typedef unsigned int u32;

__device__ __forceinline__ u16 f2bf(float f) {
    union { float f; u32 u; } v; v.f = f;
    return (u16)((v.u + 0x7FFFu + ((v.u >> 16) & 1u)) >> 16);
}

__device__ __forceinline__ void gload_lds16(const void* g, void* l) {
    __builtin_amdgcn_global_load_lds(
        (const __attribute__((address_space(1))) u32*)g,
        (__attribute__((address_space(3))) u32*)l, 16, 0, 0);
}

// ---------------- routing ----------------

__global__ void init_routing(int* sorted_rid, int* counts, int* fill, int* numTiles) {
    int i = blockIdx.x * blockDim.x + threadIdx.x;
    if (i < RP_MAX) sorted_rid[i] = -1;
    if (i < NEXP) { counts[i] = 0; fill[i] = 0; }
    if (i == 0) *numTiles = 0;
}

__global__ void zero_f32(float4* p, int n4) {
    int i = blockIdx.x * blockDim.x + threadIdx.x;
    if (i < n4) p[i] = make_float4(0.f, 0.f, 0.f, 0.f);
}

__global__ void count_kernel(const int* __restrict__ te, int* counts) {
    int j = blockIdx.x * blockDim.x + threadIdx.x;
    if (j < TOKENS * 2) atomicAdd(&counts[te[j]], 1);
}

__global__ void scan_kernel(const int* __restrict__ counts, int* offs,
                            int* tileE, int* tileRow, int* numTiles) {
    if (blockIdx.x == 0 && threadIdx.x == 0) {
        int o = 0, t = 0;
        for (int e = 0; e < NEXP; e++) {
            offs[e] = o;
            int nt = (counts[e] + 127) >> 7;
            for (int i = 0; i < nt; i++) { tileE[t] = e; tileRow[t] = o + i * 128; t++; }
            o += nt * 128;
        }
        *numTiles = t;
    }
}

__global__ void scatter_kernel(const int* __restrict__ te, const int* __restrict__ offs,
                               int* fill, int* sorted_rid) {
    int j = blockIdx.x * blockDim.x + threadIdx.x;
    if (j < TOKENS * 2) {
        int e = te[j];
        int p = offs[e] + atomicAdd(&fill[e], 1);
        sorted_rid[p] = j;
    }
}

// ---------------- conversions ----------------

__global__ void convert_x(const float* __restrict__ x, u16* __restrict__ xb) {
    int i = blockIdx.x * blockDim.x + threadIdx.x;   // one thread = 8 elems
    const float4* xv = (const float4*)x;
    float4 a = xv[i * 2], b = xv[i * 2 + 1];
    union { u16 s[8]; uint4 v; } o;
    o.s[0] = f2bf(a.x); o.s[1] = f2bf(a.y); o.s[2] = f2bf(a.z); o.s[3] = f2bf(a.w);
    o.s[4] = f2bf(b.x); o.s[5] = f2bf(b.y); o.s[6] = f2bf(b.z); o.s[7] = f2bf(b.w);
    *(uint4*)(xb + (size_t)i * 8) = o.v;
}

// in: [E][K][N] f32  ->  out: [E][N][K] bf16
__global__ void transpose_conv(const float* __restrict__ in, u16* __restrict__ out,
                               int K, int N) {
    __shared__ float tile[32][33];
    int e = blockIdx.z;
    int n0 = blockIdx.x * 32, k0 = blockIdx.y * 32;
    const float* src = in + (size_t)e * K * N;
    u16* dst = out + (size_t)e * N * K;
    int tx = threadIdx.x, ty = threadIdx.y;
    #pragma unroll
    for (int j = 0; j < 32; j += 8)
        tile[ty + j][tx] = src[(size_t)(k0 + ty + j) * N + n0 + tx];
    __syncthreads();
    #pragma unroll
    for (int j = 0; j < 32; j += 8)
        dst[(size_t)(n0 + ty + j) * K + k0 + tx] = f2bf(tile[tx][ty + j]);
}

// ---------------- grouped GEMM 1: H_act = gelu(X[gather] @ w1 + b1) ----------------
// A: gathered X rows [128 x K=1024] bf16, B: W1t [E][F][H] (n-major, k-contig)
// LDS XOR swizzle (T2): physical 16B slot kc at row r holds logical slot kc^(r&7).
// Staged via pre-swizzled GLOBAL source (linear LDS dest, rule #21).

__global__ __launch_bounds__(256, 2) void gemm1_kernel(
    const u16* __restrict__ Xb, const u16* __restrict__ W1t,
    const float* __restrict__ b1, const int* __restrict__ sorted_rid,
    const int* __restrict__ tileE, const int* __restrict__ tileRow,
    const int* __restrict__ numTiles, u16* __restrict__ Hact)
{
    int mt = blockIdx.x;
    if (mt >= *numTiles) return;
    int e = tileE[mt];
    int row0 = tileRow[mt];
    int n0 = blockIdx.y * 128;

    __shared__ __align__(16) u16 As[128 * 64];
    __shared__ __align__(16) u16 Bs[128 * 64];

    int tid = threadIdx.x;
    int wave = tid >> 6, lane = tid & 63;

    const u16* gA[4]; const u16* gB[4];
    #pragma unroll
    for (int i = 0; i < 4; i++) {
        int c = i * 256 + tid;
        int r = c >> 3, kc = c & 7;
        int kcs = kc ^ (r & 7);                  // pre-swizzled source slot
        int rid = sorted_rid[row0 + r];
        int tok = rid < 0 ? 0 : (rid >> 1);
        gA[i] = Xb + (size_t)tok * HD + kcs * 8;
        gB[i] = W1t + ((size_t)e * FD + (n0 + r)) * HD + kcs * 8;
    }
    char* AsB = (char*)As; char* BsB = (char*)Bs;

    f32x4 acc[4][4] = {};

    int wr = wave >> 1, wc = wave & 1;
    // swizzled read offsets: row&7 == lane&7 for all m
    int off0 = (((lane >> 4) ^ (lane & 7)) << 4);
    int off1 = off0 ^ 64;
    const char* Abase = AsB + (wr * 64 + (lane & 15)) * 128;
    const char* Bbase = BsB + (wc * 64 + (lane & 15)) * 128;

    for (int kt = 0; kt < HD / 64; kt++) {
        #pragma unroll
        for (int i = 0; i < 4; i++)
            gload_lds16(gA[i], AsB + i * 4096 + wave * 1024);
        #pragma unroll
        for (int i = 0; i < 4; i++)
            gload_lds16(gB[i], BsB + i * 4096 + wave * 1024);
        #pragma unroll
        for (int i = 0; i < 4; i++) { gA[i] += 64; gB[i] += 64; }
        __syncthreads();   // drains vmcnt(0) -> staged tile visible
        #pragma unroll
        for (int kk = 0; kk < 2; kk++) {
            int off = kk ? off1 : off0;
            bf16x8 a[4], b[4];
            #pragma unroll
            for (int m = 0; m < 4; m++) a[m] = *(const bf16x8*)(Abase + m * 2048 + off);
            #pragma unroll
            for (int n = 0; n < 4; n++) b[n] = *(const bf16x8*)(Bbase + n * 2048 + off);
            #pragma unroll
            for (int m = 0; m < 4; m++)
                #pragma unroll
                for (int n = 0; n < 4; n++)
                    acc[m][n] = __builtin_amdgcn_mfma_f32_16x16x32_bf16(a[m], b[n], acc[m][n], 0, 0, 0);
        }
        __syncthreads();   // all waves done reading before next stage
    }

    // epilogue: bias + exact gelu -> bf16 store
    const float* b1e = b1 + e * FD + n0;
    #pragma unroll
    for (int n = 0; n < 4; n++) {
        int col = wc * 64 + n * 16 + (lane & 15);
        float bias = b1e[col];
        #pragma unroll
        for (int m = 0; m < 4; m++) {
            int rbase = wr * 64 + m * 16 + (lane >> 4) * 4;
            #pragma unroll
            for (int r = 0; r < 4; r++) {
                float v = acc[m][n][r] + bias;
                v = 0.5f * v * (1.0f + erff(v * 0.70710678118f));
                Hact[(size_t)(row0 + rbase + r) * FD + n0 + col] = f2bf(v);
            }
        }
    }
}

// ---------------- grouped GEMM 2: y += fw * (H_act @ w2 + b2) ----------------
// A: Hact [rows x K=2048] bf16 (contig), B: W2t [E][H][F] (n-major, k-contig)

__global__ __launch_bounds__(256, 2) void gemm2_kernel(
    const u16* __restrict__ Hact, const u16* __restrict__ W2t,
    const float* __restrict__ b2, const float* __restrict__ ew,
    const int* __restrict__ sorted_rid,
    const int* __restrict__ tileE, const int* __restrict__ tileRow,
    const int* __restrict__ numTiles, float* __restrict__ y)
{
    int mt = blockIdx.x;
    if (mt >= *numTiles) return;
    int e = tileE[mt];
    int row0 = tileRow[mt];
    int n0 = blockIdx.y * 128;

    __shared__ __align__(16) u16 As[128 * 64];
    __shared__ __align__(16) u16 Bs[128 * 64];

    int tid = threadIdx.x;
    int wave = tid >> 6, lane = tid & 63;

    const u16* gA[4]; const u16* gB[4];
    #pragma unroll
    for (int i = 0; i < 4; i++) {
        int c = i * 256 + tid;
        int r = c >> 3, kc = c & 7;
        int kcs = kc ^ (r & 7);                  // pre-swizzled source slot
        gA[i] = Hact + (size_t)(row0 + r) * FD + kcs * 8;
        gB[i] = W2t + ((size_t)e * HD + (n0 + r)) * FD + kcs * 8;
    }
    char* AsB = (char*)As; char* BsB = (char*)Bs;

    f32x4 acc[4][4] = {};

    int wr = wave >> 1, wc = wave & 1;
    int off0 = (((lane >> 4) ^ (lane & 7)) << 4);
    int off1 = off0 ^ 64;
    const char* Abase = AsB + (wr * 64 + (lane & 15)) * 128;
    const char* Bbase = BsB + (wc * 64 + (lane & 15)) * 128;

    for (int kt = 0; kt < FD / 64; kt++) {
        #pragma unroll
        for (int i = 0; i < 4; i++)
            gload_lds16(gA[i], AsB + i * 4096 + wave * 1024);
        #pragma unroll
        for (int i = 0; i < 4; i++)
            gload_lds16(gB[i], BsB + i * 4096 + wave * 1024);
        #pragma unroll
        for (int i = 0; i < 4; i++) { gA[i] += 64; gB[i] += 64; }
        __syncthreads();
        #pragma unroll
        for (int kk = 0; kk < 2; kk++) {
            int off = kk ? off1 : off0;
            bf16x8 a[4], b[4];
            #pragma unroll
            for (int m = 0; m < 4; m++) a[m] = *(const bf16x8*)(Abase + m * 2048 + off);
            #pragma unroll
            for (int n = 0; n < 4; n++) b[n] = *(const bf16x8*)(Bbase + n * 2048 + off);
            #pragma unroll
            for (int m = 0; m < 4; m++)
                #pragma unroll
                for (int n = 0; n < 4; n++)
                    acc[m][n] = __builtin_amdgcn_mfma_f32_16x16x32_bf16(a[m], b[n], acc[m][n], 0, 0, 0);
        }
        __syncthreads();
    }

    // epilogue: bias, routing weight, atomic scatter-add into y[token]
    const float* b2e = b2 + e * HD + n0;
    #pragma unroll
    for (int m = 0; m < 4; m++) {
        int rbase = wr * 64 + m * 16 + (lane >> 4) * 4;
        #pragma unroll
        for (int r = 0; r < 4; r++) {
            int rid = sorted_rid[row0 + rbase + r];
            if (rid < 0) continue;               // padding row
            float fw = ew[rid];
            float* yrow = y + (size_t)(rid >> 1) * HD + n0;
            #pragma unroll
            for (int n = 0; n < 4; n++) {
                int col = wc * 64 + n * 16 + (lane & 15);
                float v = (acc[m][n][r] + b2e[col]) * fw;
                atomicAdd(&yrow[col], v);
            }
        }
    }
}

// ---------------- launch ----------------

extern "C" void kernel_launch(void* const* d_in, const int* in_sizes, int n_in,
                              void* d_out, int out_size, void* d_ws, size_t ws_size,
                              hipStream_t stream) {
    const float* x  = (const float*)d_in[0];
    const float* ew = (const float*)d_in[1];
    const int*   te = (const int*)d_in[2];
    const float* w1 = (const float*)d_in[3];
    const float* b1 = (const float*)d_in[4];
    const float* w2 = (const float*)d_in[5];
    const float* b2 = (const float*)d_in[6];
    float* y = (float*)d_out;

    char* ws = (char*)d_ws;
    u16* Xb   = (u16*)(ws);                      // 33,554,432 B
    u16* W1t  = (u16*)(ws + 33554432);           // 33,554,432 B
    u16* W2t  = (u16*)(ws + 67108864);           // 33,554,432 B
    u16* Hact = (u16*)(ws + 100663296);          // 138,412,032 B
    char* ip  = ws + 239075328;
    int* counts   = (int*)(ip);
    int* fill     = (int*)(ip + 32);
    int* offs     = (int*)(ip + 64);
    int* numTiles = (int*)(ip + 96);
    int* tileE    = (int*)(ip + 128);
    int* tileRow  = (int*)(ip + 128 + 1056);
    int* sorted   = (int*)(ip + 4096);           // RP_MAX ints

    // routing
    init_routing<<<(RP_MAX + 255) / 256, 256, 0, stream>>>(sorted, counts, fill, numTiles);
    zero_f32<<<(out_size / 4 + 255) / 256, 256, 0, stream>>>((float4*)y, out_size / 4);
    count_kernel<<<(TOKENS * 2 + 255) / 256, 256, 0, stream>>>(te, counts);
    scan_kernel<<<1, 64, 0, stream>>>(counts, offs, tileE, tileRow, numTiles);
    scatter_kernel<<<(TOKENS * 2 + 255) / 256, 256, 0, stream>>>(te, offs, fill, sorted);

    // conversions
    convert_x<<<(TOKENS * HD / 8 + 255) / 256, 256, 0, stream>>>(x, Xb);
    transpose_conv<<<dim3(FD / 32, HD / 32, NEXP), dim3(32, 8), 0, stream>>>(w1, W1t, HD, FD);
    transpose_conv<<<dim3(HD / 32, FD / 32, NEXP), dim3(32, 8), 0, stream>>>(w2, W2t, FD, HD);

    // grouped GEMMs
    gemm1_kernel<<<dim3(MAX_MT, FD / 128), 256, 0, stream>>>(
        Xb, W1t, b1, sorted, tileE, tileRow, numTiles, Hact);
    gemm2_kernel<<<dim3(MAX_MT, HD / 128), 256, 0, stream>>>(
        Hact, W2t, b2, ew, sorted, tileE, tileRow, numTiles, y);
}